// Round 2
// baseline (1844.372 us; speedup 1.0000x reference)
//
#include <hip/hip_runtime.h>

// ---------------------------------------------------------------------------
// MoChA: monotonic chunkwise attention. B=16, K=2000(pad 2048), Q=256, D=1024,
// H=4, dk=256, W=8, SCALE=32, r=-4.
// Workspace budget ~219 MiB (round-1 crashed at ~545 MiB -> suspected ws OOB):
//   wt[6] 12M | kproj 62.5M | qproj 8M | bufP 64M (p->eca->beta, bf16)
//   bufA 64M (alpha->vT, bf16) | cv 8M
// cp is computed inside the scan (no 128 MiB cp buffer); scan state fp32 regs.
// ---------------------------------------------------------------------------

typedef __bf16 bf16x8_t __attribute__((ext_vector_type(8)));
typedef float f32x4_t __attribute__((ext_vector_type(4)));
typedef unsigned short ushort8_t __attribute__((ext_vector_type(8)));

#define LDS_STRIDE 40  // 32 data + 8 pad bf16 -> 80 B rows, 16B-aligned

__device__ __forceinline__ unsigned short f2bf(float x) {
  unsigned int u = __builtin_bit_cast(unsigned int, x);
  u += 0x7fffu + ((u >> 16) & 1u);  // RNE
  return (unsigned short)(u >> 16);
}
__device__ __forceinline__ float bf2f(unsigned short h) {
  unsigned int u = ((unsigned int)h) << 16;
  return __builtin_bit_cast(float, u);
}

// ---- core 128x128 MFMA tile, both operands bf16, BT layout ----------------
__device__ __forceinline__ void gemm_bt_tile(
    const unsigned short* __restrict__ A, long lda,
    const unsigned short* __restrict__ B, long ldb, int brow_valid,
    int Kd, unsigned short* lA, unsigned short* lB, f32x4_t acc[4][4]) {
  const int tid = threadIdx.x;
  const int lane = tid & 63;
  const int wid = tid >> 6;
  const int wm = wid >> 1, wn = wid & 1;
  const int lr = lane & 15, quad = lane >> 4;
  for (int ks = 0; ks < Kd; ks += 32) {
    __syncthreads();
#pragma unroll
    for (int c = 0; c < 2; ++c) {
      int chunk = tid + c * 256;
      int row = chunk >> 2;
      int kc = (chunk & 3) << 3;
      ushort8_t va = *(const ushort8_t*)(A + (long)row * lda + ks + kc);
      *(ushort8_t*)(lA + row * LDS_STRIDE + kc) = va;
      ushort8_t vb;
#pragma unroll
      for (int z = 0; z < 8; ++z) vb[z] = 0;
      if (row < brow_valid) vb = *(const ushort8_t*)(B + (long)row * ldb + ks + kc);
      *(ushort8_t*)(lB + row * LDS_STRIDE + kc) = vb;
    }
    __syncthreads();
    bf16x8_t afr[4], bfr[4];
#pragma unroll
    for (int i = 0; i < 4; ++i)
      afr[i] = *(const bf16x8_t*)(lA + (wm * 64 + i * 16 + lr) * LDS_STRIDE + quad * 8);
#pragma unroll
    for (int j = 0; j < 4; ++j)
      bfr[j] = *(const bf16x8_t*)(lB + (wn * 64 + j * 16 + lr) * LDS_STRIDE + quad * 8);
#pragma unroll
    for (int i = 0; i < 4; ++i)
#pragma unroll
      for (int j = 0; j < 4; ++j)
        acc[i][j] = __builtin_amdgcn_mfma_f32_16x16x32_bf16(afr[i], bfr[j], acc[i][j], 0, 0, 0);
  }
}

// ---- variant: A is fp32 (converted to bf16 during staging), B bf16 full ----
__device__ __forceinline__ void gemm_bt_tile_f32A(
    const float* __restrict__ A, long lda,
    const unsigned short* __restrict__ B, long ldb,
    int Kd, unsigned short* lA, unsigned short* lB, f32x4_t acc[4][4]) {
  const int tid = threadIdx.x;
  const int lane = tid & 63;
  const int wid = tid >> 6;
  const int wm = wid >> 1, wn = wid & 1;
  const int lr = lane & 15, quad = lane >> 4;
  for (int ks = 0; ks < Kd; ks += 32) {
    __syncthreads();
#pragma unroll
    for (int c = 0; c < 2; ++c) {
      int chunk = tid + c * 256;
      int row = chunk >> 2;
      int kc = (chunk & 3) << 3;
      const float* ap = A + (long)row * lda + ks + kc;
      float4 f0 = *(const float4*)ap;
      float4 f1 = *(const float4*)(ap + 4);
      ushort8_t va;
      va[0] = f2bf(f0.x); va[1] = f2bf(f0.y); va[2] = f2bf(f0.z); va[3] = f2bf(f0.w);
      va[4] = f2bf(f1.x); va[5] = f2bf(f1.y); va[6] = f2bf(f1.z); va[7] = f2bf(f1.w);
      *(ushort8_t*)(lA + row * LDS_STRIDE + kc) = va;
      ushort8_t vb = *(const ushort8_t*)(B + (long)row * ldb + ks + kc);
      *(ushort8_t*)(lB + row * LDS_STRIDE + kc) = vb;
    }
    __syncthreads();
    bf16x8_t afr[4], bfr[4];
#pragma unroll
    for (int i = 0; i < 4; ++i)
      afr[i] = *(const bf16x8_t*)(lA + (wm * 64 + i * 16 + lr) * LDS_STRIDE + quad * 8);
#pragma unroll
    for (int j = 0; j < 4; ++j)
      bfr[j] = *(const bf16x8_t*)(lB + (wn * 64 + j * 16 + lr) * LDS_STRIDE + quad * 8);
#pragma unroll
    for (int i = 0; i < 4; ++i)
#pragma unroll
      for (int j = 0; j < 4; ++j)
        acc[i][j] = __builtin_amdgcn_mfma_f32_16x16x32_bf16(afr[i], bfr[j], acc[i][j], 0, 0, 0);
  }
}

#define EPILOGUE_IDX()                                          \
  const int tid = threadIdx.x, lane = tid & 63, wid = tid >> 6; \
  const int wm = wid >> 1, wn = wid & 1, lr = lane & 15, quad = lane >> 4;

#define ACC_INIT()            \
  f32x4_t acc[4][4];          \
  _Pragma("unroll") for (int i = 0; i < 4; ++i)     \
  _Pragma("unroll") for (int j = 0; j < 4; ++j)     \
  _Pragma("unroll") for (int r = 0; r < 4; ++r) acc[i][j][r] = 0.f;

// ---- projection: C_bf16 = bf16(A_f32 @ Wt^T + bias), N=1024 ---------------
__global__ __launch_bounds__(256) void k_proj(const float* __restrict__ A,
                                              const unsigned short* __restrict__ Wt,
                                              const float* __restrict__ bias,
                                              unsigned short* __restrict__ C) {
  __shared__ __attribute__((aligned(16))) unsigned short lA[128 * LDS_STRIDE];
  __shared__ __attribute__((aligned(16))) unsigned short lB[128 * LDS_STRIDE];
  ACC_INIT();
  const float* Ab = A + (long)blockIdx.y * 128 * 1024;
  const unsigned short* Bb = Wt + (long)blockIdx.x * 128 * 1024;
  gemm_bt_tile_f32A(Ab, 1024, Bb, 1024, 1024, lA, lB, acc);
  EPILOGUE_IDX();
  long mbase = (long)blockIdx.y * 128;
  int nbase = blockIdx.x * 128;
#pragma unroll
  for (int j = 0; j < 4; ++j) {
    int cg = nbase + wn * 64 + j * 16 + lr;
    float bvv = bias[cg];
#pragma unroll
    for (int i = 0; i < 4; ++i)
#pragma unroll
      for (int r = 0; r < 4; ++r) {
        long mg = mbase + wm * 64 + i * 16 + quad * 4 + r;
        C[mg * 1024 + cg] = f2bf(acc[i][j][r] + bvv);
      }
  }
}

// ---- attention scores -> bf16. is_ma: sigmoid(e/32+r) masked; else e/32|NEG.
__global__ __launch_bounds__(256) void k_escore(const unsigned short* __restrict__ qproj,
                                                const unsigned short* __restrict__ kproj,
                                                const int* __restrict__ mask,
                                                const float* __restrict__ rptr,
                                                unsigned short* __restrict__ outp, int is_ma) {
  __shared__ __attribute__((aligned(16))) unsigned short lA[128 * LDS_STRIDE];
  __shared__ __attribute__((aligned(16))) unsigned short lB[128 * LDS_STRIDE];
  ACC_INIT();
  int bz = blockIdx.z, b = bz >> 2, h = bz & 3;
  int nrow0 = blockIdx.x * 128;
  const unsigned short* Ab = qproj + ((long)b * 256 + blockIdx.y * 128) * 1024 + h * 256;
  const unsigned short* Bb = kproj + ((long)b * 2000 + nrow0) * 1024 + h * 256;
  int bval = 2000 - nrow0;
  if (bval > 128) bval = 128;
  if (bval < 0) bval = 0;
  gemm_bt_tile(Ab, 1024, Bb, 1024, bval, 256, lA, lB, acc);
  float rv = is_ma ? rptr[0] : 0.f;
  EPILOGUE_IDX();
#pragma unroll
  for (int j = 0; j < 4; ++j) {
    int kg = nrow0 + wn * 64 + j * 16 + lr;
#pragma unroll
    for (int i = 0; i < 4; ++i)
#pragma unroll
      for (int r = 0; r < 4; ++r) {
        int qg = blockIdx.y * 128 + wm * 64 + i * 16 + quad * 4 + r;
        float e = acc[i][j][r] * 0.03125f;
        bool valid = false;
        if (kg < 2000) valid = (mask[((long)b * 256 + qg) * 2000 + kg] != 0);
        float ov;
        if (is_ma)
          ov = valid ? (1.f / (1.f + __expf(-(e + rv)))) : 0.f;
        else
          ov = valid ? e : -1e9f;
        outp[((long)bz * 256 + qg) * 2048 + kg] = f2bf(ov);
      }
  }
}

// ---- sequential scan over q; cp computed in-kernel; aw state fp32 regs ----
__global__ __launch_bounds__(256) void k_scan(const unsigned short* __restrict__ p,
                                              const float* __restrict__ awp,
                                              unsigned short* __restrict__ alpha) {
  __shared__ float ws1[4];
  __shared__ float ws2[4];
  int bh = blockIdx.x;
  int tid = threadIdx.x, lane = tid & 63, wid = tid >> 6;
  long base = (long)bh * 256 * 2048 + tid * 8;
  float aw[8];
  const float* ap = awp + (long)bh * 2000;
#pragma unroll
  for (int i = 0; i < 8; ++i) {
    int k = tid * 8 + i;
    aw[i] = (k < 2000) ? ap[k] : 0.f;
  }
  const unsigned short* prow = p + base;
  unsigned short* arow = alpha + base;
  ushort8_t pcur = *(const ushort8_t*)prow;
  for (int q = 0; q < 256; ++q) {
    ushort8_t pnext = pcur;
    if (q < 255) pnext = *(const ushort8_t*)(prow + (long)(q + 1) * 2048);
    float pv[8];
#pragma unroll
    for (int i = 0; i < 8; ++i) pv[i] = bf2f((unsigned short)pcur[i]);
    // scan 1: cp = exp(exclusive cumsum of log(clip(1-p)))
    float lex[8], s1 = 0.f;
#pragma unroll
    for (int i = 0; i < 8; ++i) {
      float om = fminf(fmaxf(1.f - pv[i], 1e-6f), 1.f);
      lex[i] = s1;
      s1 += __logf(om);
    }
    float incl1 = s1;
    for (int d = 1; d < 64; d <<= 1) {
      float y = __shfl_up(incl1, (unsigned)d, 64);
      if (lane >= d) incl1 += y;
    }
    if (lane == 63) ws1[wid] = incl1;
    __syncthreads();
    float off1 = incl1 - s1;
    if (wid > 0) off1 += ws1[0];
    if (wid > 1) off1 += ws1[1];
    if (wid > 2) off1 += ws1[2];
    // scan 2: t = inclusive cumsum of aw/clip(cp)
    float cpv[8], t[8], s2 = 0.f;
#pragma unroll
    for (int i = 0; i < 8; ++i) {
      cpv[i] = __expf(off1 + lex[i]);
      float den = fminf(fmaxf(cpv[i], 1e-6f), 1.f);
      s2 += aw[i] * __builtin_amdgcn_rcpf(den);
      t[i] = s2;
    }
    float incl2 = s2;
    for (int d = 1; d < 64; d <<= 1) {
      float y = __shfl_up(incl2, (unsigned)d, 64);
      if (lane >= d) incl2 += y;
    }
    if (lane == 63) ws2[wid] = incl2;
    __syncthreads();
    float off2 = incl2 - s2;
    if (wid > 0) off2 += ws2[0];
    if (wid > 1) off2 += ws2[1];
    if (wid > 2) off2 += ws2[2];
    ushort8_t o;
#pragma unroll
    for (int i = 0; i < 8; ++i) {
      aw[i] = pv[i] * cpv[i] * (t[i] + off2);
      o[i] = f2bf(aw[i]);
    }
    *(ushort8_t*)(arow + (long)q * 2048) = o;
    pcur = pnext;
  }
}

// ---- beta = se * movsum_fwd7(alpha / movsum_back7(se)); in-place over eca --
__global__ __launch_bounds__(256) void k_beta(unsigned short* __restrict__ eca,
                                              const unsigned short* __restrict__ alpha) {
  __shared__ float sse[2048];
  __shared__ float sra[2048];
  __shared__ float red[4];
  long base = (long)blockIdx.x * 2048;
  int tid = threadIdx.x, lane = tid & 63, wid = tid >> 6;
  ushort8_t u8 = *(const ushort8_t*)(eca + base + tid * 8);
  ushort8_t a8 = *(const ushort8_t*)(alpha + base + tid * 8);
  float u[8], a[8];
#pragma unroll
  for (int i = 0; i < 8; ++i) {
    u[i] = bf2f((unsigned short)u8[i]);
    a[i] = bf2f((unsigned short)a8[i]);
  }
  float m = u[0];
#pragma unroll
  for (int i = 1; i < 8; ++i) m = fmaxf(m, u[i]);
  for (int d = 1; d < 64; d <<= 1) m = fmaxf(m, __shfl_xor(m, d, 64));
  if (lane == 0) red[wid] = m;
  __syncthreads();
  m = fmaxf(fmaxf(red[0], red[1]), fmaxf(red[2], red[3]));
  float se[8];
#pragma unroll
  for (int i = 0; i < 8; ++i) {
    se[i] = fmaxf(__expf(u[i] - m), 1e-5f);
    sse[tid * 8 + i] = se[i];
  }
  __syncthreads();
#pragma unroll
  for (int i = 0; i < 8; ++i) {
    int k = tid * 8 + i;
    float s = 0.f;
#pragma unroll
    for (int dd = 0; dd < 8; ++dd) {
      int j = k - dd;
      if (j >= 0) s += sse[j];
    }
    sra[k] = a[i] * __builtin_amdgcn_rcpf(s);
  }
  __syncthreads();
  ushort8_t o;
#pragma unroll
  for (int i = 0; i < 8; ++i) {
    int k = tid * 8 + i;
    float s = 0.f;
#pragma unroll
    for (int dd = 0; dd < 8; ++dd) {
      int j = k + dd;
      if (j <= 2047) s += sra[j];
    }
    o[i] = f2bf(se[i] * s);
  }
  *(ushort8_t*)(eca + base + tid * 8) = o;
}

// ---- vT[bz][d][k] = vproj[b*2000+k][h*256+d], k pad 2048 ------------------
__global__ __launch_bounds__(256) void k_build_vT(const unsigned short* __restrict__ v,
                                                  unsigned short* __restrict__ vT) {
  __shared__ unsigned short t[64][72];
  int bz = blockIdx.z, b = bz >> 2, h = bz & 3;
  int k0 = blockIdx.x * 64, d0 = blockIdx.y * 64;
  int tx = threadIdx.x & 63, tg = threadIdx.x >> 6;
#pragma unroll
  for (int i = 0; i < 16; ++i) {
    int kk = tg * 16 + i;
    int k = k0 + kk;
    unsigned short val = 0;
    if (k < 2000) val = v[((long)(b * 2000 + k)) * 1024 + h * 256 + d0 + tx];
    t[kk][tx] = val;
  }
  __syncthreads();
#pragma unroll
  for (int i = 0; i < 16; ++i) {
    int dd = tg * 16 + i;
    vT[((long)bz * 256 + d0 + dd) * 2048 + k0 + tx] = t[tx][dd];
  }
}

// ---- cv = beta @ v (per bz: 256x2048 @ 2048x256), bf16 out ----------------
__global__ __launch_bounds__(256) void k_cv(const unsigned short* __restrict__ beta,
                                            const unsigned short* __restrict__ vT,
                                            unsigned short* __restrict__ cv) {
  __shared__ __attribute__((aligned(16))) unsigned short lA[128 * LDS_STRIDE];
  __shared__ __attribute__((aligned(16))) unsigned short lB[128 * LDS_STRIDE];
  ACC_INIT();
  int bz = blockIdx.z, b = bz >> 2, h = bz & 3;
  const unsigned short* Ab = beta + (long)bz * 256 * 2048 + (long)blockIdx.y * 128 * 2048;
  const unsigned short* Bb = vT + (long)bz * 256 * 2048 + (long)blockIdx.x * 128 * 2048;
  gemm_bt_tile(Ab, 2048, Bb, 2048, 128, 2048, lA, lB, acc);
  EPILOGUE_IDX();
#pragma unroll
  for (int j = 0; j < 4; ++j) {
    int cg = h * 256 + blockIdx.x * 128 + wn * 64 + j * 16 + lr;
#pragma unroll
    for (int i = 0; i < 4; ++i)
#pragma unroll
      for (int r = 0; r < 4; ++r) {
        long mg = (long)b * 256 + blockIdx.y * 128 + wm * 64 + i * 16 + quad * 4 + r;
        cv[mg * 1024 + cg] = f2bf(acc[i][j][r]);
      }
  }
}

// ---- out = cv @ WoT^T + bo, fp32, M=4096 N=1024 ---------------------------
__global__ __launch_bounds__(256) void k_out(const unsigned short* __restrict__ cv,
                                             const unsigned short* __restrict__ WoT,
                                             const float* __restrict__ bo,
                                             float* __restrict__ outp) {
  __shared__ __attribute__((aligned(16))) unsigned short lA[128 * LDS_STRIDE];
  __shared__ __attribute__((aligned(16))) unsigned short lB[128 * LDS_STRIDE];
  ACC_INIT();
  const unsigned short* Ab = cv + (long)blockIdx.y * 128 * 1024;
  const unsigned short* Bb = WoT + (long)blockIdx.x * 128 * 1024;
  gemm_bt_tile(Ab, 1024, Bb, 1024, 128, 1024, lA, lB, acc);
  EPILOGUE_IDX();
#pragma unroll
  for (int j = 0; j < 4; ++j) {
    int cg = blockIdx.x * 128 + wn * 64 + j * 16 + lr;
    float bvv = bo[cg];
#pragma unroll
    for (int i = 0; i < 4; ++i)
#pragma unroll
      for (int r = 0; r < 4; ++r) {
        long mg = (long)blockIdx.y * 128 + wm * 64 + i * 16 + quad * 4 + r;
        outp[mg * 1024 + cg] = acc[i][j][r] + bvv;
      }
  }
}

// ---- W(1024x1024 f32) -> Wt bf16, Wt[n][d] = W[d][n] ----------------------
__global__ __launch_bounds__(256) void k_twT(const float* __restrict__ W,
                                             unsigned short* __restrict__ Wt) {
  __shared__ float t[32][33];
  int bx = blockIdx.x, by = blockIdx.y;
  int lx = threadIdx.x & 31, ly = threadIdx.x >> 5;
#pragma unroll
  for (int r = 0; r < 4; ++r)
    t[ly + 8 * r][lx] = W[((long)(by * 32 + ly + 8 * r)) * 1024 + bx * 32 + lx];
  __syncthreads();
#pragma unroll
  for (int r = 0; r < 4; ++r)
    Wt[((long)(bx * 32 + ly + 8 * r)) * 1024 + by * 32 + lx] = f2bf(t[lx][ly + 8 * r]);
}

// ---------------------------------------------------------------------------
extern "C" void kernel_launch(void* const* d_in, const int* in_sizes, int n_in,
                              void* d_out, int out_size, void* d_ws, size_t ws_size,
                              hipStream_t stream) {
  const float* key = (const float*)d_in[0];
  const float* value = (const float*)d_in[1];
  const float* query = (const float*)d_in[2];
  const int* mask = (const int*)d_in[3];
  const float* awp = (const float*)d_in[4];
  const float* Wk_ma = (const float*)d_in[5];
  const float* bk_ma = (const float*)d_in[6];
  const float* Wq_ma = (const float*)d_in[7];
  const float* bq_ma = (const float*)d_in[8];
  const float* rvec = (const float*)d_in[9];
  const float* Wk_ca = (const float*)d_in[10];
  const float* bk_ca = (const float*)d_in[11];
  const float* Wq_ca = (const float*)d_in[12];
  const float* bq_ca = (const float*)d_in[13];
  const float* Wv = (const float*)d_in[14];
  const float* bv = (const float*)d_in[15];
  const float* Wo = (const float*)d_in[16];
  const float* bo = (const float*)d_in[17];
  float* outp = (float*)d_out;
  (void)in_sizes; (void)n_in; (void)out_size;

  // workspace arena, ~219 MiB total
  char* ws = (char*)d_ws;
  size_t off = 0;
  auto alloc = [&](size_t bytes) {
    void* pp = ws + off;
    off += (bytes + 255) & ~(size_t)255;
    return pp;
  };
  unsigned short* wt[6];
  for (int i = 0; i < 6; ++i) wt[i] = (unsigned short*)alloc(1024L * 1024 * 2);
  unsigned short* kproj = (unsigned short*)alloc(32000L * 1024 * 2);  // k_ma -> k_ca -> v
  unsigned short* qproj = (unsigned short*)alloc(4096L * 1024 * 2);   // q_ma -> q_ca
  unsigned short* bufP = (unsigned short*)alloc(64L * 256 * 2048 * 2);  // p -> eca -> beta
  unsigned short* bufA = (unsigned short*)alloc(64L * 256 * 2048 * 2);  // alpha -> vT
  unsigned short* cv_bf = (unsigned short*)alloc(4096L * 1024 * 2);
  if (ws_size < off) return;  // ws too small: fail loudly via absmax, not a fault

  dim3 blk(256);
  // weights
  k_twT<<<dim3(32, 32), blk, 0, stream>>>(Wk_ma, wt[0]);
  k_twT<<<dim3(32, 32), blk, 0, stream>>>(Wq_ma, wt[1]);
  k_twT<<<dim3(32, 32), blk, 0, stream>>>(Wk_ca, wt[2]);
  k_twT<<<dim3(32, 32), blk, 0, stream>>>(Wq_ca, wt[3]);
  k_twT<<<dim3(32, 32), blk, 0, stream>>>(Wv, wt[4]);
  k_twT<<<dim3(32, 32), blk, 0, stream>>>(Wo, wt[5]);
  // MA: projections -> p -> scan -> alpha
  k_proj<<<dim3(8, 250), blk, 0, stream>>>(key, wt[0], bk_ma, kproj);
  k_proj<<<dim3(8, 32), blk, 0, stream>>>(query, wt[1], bq_ma, qproj);
  k_escore<<<dim3(16, 2, 64), blk, 0, stream>>>(qproj, kproj, mask, rvec, bufP, 1);
  k_scan<<<dim3(64), blk, 0, stream>>>(bufP, awp, bufA);
  // CA: projections -> eca (reuses bufP) -> beta (in-place)
  k_proj<<<dim3(8, 250), blk, 0, stream>>>(key, wt[2], bk_ca, kproj);
  k_proj<<<dim3(8, 32), blk, 0, stream>>>(query, wt[3], bq_ca, qproj);
  k_escore<<<dim3(16, 2, 64), blk, 0, stream>>>(qproj, kproj, mask, rvec, bufP, 0);
  k_beta<<<dim3(16384), blk, 0, stream>>>(bufP, bufA);
  // value path (vT reuses bufA after alpha consumed)
  k_proj<<<dim3(8, 250), blk, 0, stream>>>(value, wt[4], bv, kproj);
  k_build_vT<<<dim3(32, 4, 64), blk, 0, stream>>>(kproj, bufA);
  // context + output
  k_cv<<<dim3(2, 2, 64), blk, 0, stream>>>(bufP, bufA, cv_bf);
  k_out<<<dim3(8, 32), blk, 0, stream>>>(cv_bf, wt[5], bo, outp);
}

// Round 3
// 1705.613 us; speedup vs baseline: 1.0814x; 1.0814x over previous
//
#include <hip/hip_runtime.h>

// ---------------------------------------------------------------------------
// MoChA: monotonic chunkwise attention. B=16, K=2000(pad 2048), Q=256, D=1024,
// H=4, dk=256, W=8, SCALE=32, r=-4.
// R3: scan overhaul. cp = exp(excl_cumsum(log1mp)) hoisted out of the
// sequential q-loop into parallel k_cp (stored bf16, aliasing the dead
// kproj/qproj region). Wave prefix sums via DPP (row_shr + bcast) instead of
// ds_bpermute shfl chains (~120cyc each). One barrier per q-step.
// Arena stays ~219 MiB (R1 crashed at 545 MiB -> ws OOB).
// ---------------------------------------------------------------------------

typedef __bf16 bf16x8_t __attribute__((ext_vector_type(8)));
typedef float f32x4_t __attribute__((ext_vector_type(4)));
typedef unsigned short ushort8_t __attribute__((ext_vector_type(8)));

#define LDS_STRIDE 40  // 32 data + 8 pad bf16 -> 80 B rows, 16B-aligned

__device__ __forceinline__ unsigned short f2bf(float x) {
  unsigned int u = __builtin_bit_cast(unsigned int, x);
  u += 0x7fffu + ((u >> 16) & 1u);  // RNE
  return (unsigned short)(u >> 16);
}
__device__ __forceinline__ float bf2f(unsigned short h) {
  unsigned int u = ((unsigned int)h) << 16;
  return __builtin_bit_cast(float, u);
}

// 64-lane inclusive prefix sum, 6 DPP steps (full-rate VALU, no LDS).
__device__ __forceinline__ float wave_incl_scan(float x) {
  float v = x;
  int mv;
#define DPP_ADD(ctrl, rmask, bctrl)                                           \
  mv = __builtin_amdgcn_update_dpp(0, __builtin_bit_cast(int, v), ctrl,       \
                                   rmask, 0xf, bctrl);                        \
  v += __builtin_bit_cast(float, mv);
  DPP_ADD(0x111, 0xf, true);   // row_shr:1
  DPP_ADD(0x112, 0xf, true);   // row_shr:2
  DPP_ADD(0x114, 0xf, true);   // row_shr:4
  DPP_ADD(0x118, 0xf, true);   // row_shr:8  -> prefix within each row of 16
  DPP_ADD(0x142, 0xa, false);  // bcast15 -> rows 1,3
  DPP_ADD(0x143, 0xc, false);  // bcast31 -> rows 2,3
#undef DPP_ADD
  return v;
}

// ---- core 128x128 MFMA tile, both operands bf16, BT layout ----------------
__device__ __forceinline__ void gemm_bt_tile(
    const unsigned short* __restrict__ A, long lda,
    const unsigned short* __restrict__ B, long ldb, int brow_valid,
    int Kd, unsigned short* lA, unsigned short* lB, f32x4_t acc[4][4]) {
  const int tid = threadIdx.x;
  const int lane = tid & 63;
  const int wid = tid >> 6;
  const int wm = wid >> 1, wn = wid & 1;
  const int lr = lane & 15, quad = lane >> 4;
  for (int ks = 0; ks < Kd; ks += 32) {
    __syncthreads();
#pragma unroll
    for (int c = 0; c < 2; ++c) {
      int chunk = tid + c * 256;
      int row = chunk >> 2;
      int kc = (chunk & 3) << 3;
      ushort8_t va = *(const ushort8_t*)(A + (long)row * lda + ks + kc);
      *(ushort8_t*)(lA + row * LDS_STRIDE + kc) = va;
      ushort8_t vb;
#pragma unroll
      for (int z = 0; z < 8; ++z) vb[z] = 0;
      if (row < brow_valid) vb = *(const ushort8_t*)(B + (long)row * ldb + ks + kc);
      *(ushort8_t*)(lB + row * LDS_STRIDE + kc) = vb;
    }
    __syncthreads();
    bf16x8_t afr[4], bfr[4];
#pragma unroll
    for (int i = 0; i < 4; ++i)
      afr[i] = *(const bf16x8_t*)(lA + (wm * 64 + i * 16 + lr) * LDS_STRIDE + quad * 8);
#pragma unroll
    for (int j = 0; j < 4; ++j)
      bfr[j] = *(const bf16x8_t*)(lB + (wn * 64 + j * 16 + lr) * LDS_STRIDE + quad * 8);
#pragma unroll
    for (int i = 0; i < 4; ++i)
#pragma unroll
      for (int j = 0; j < 4; ++j)
        acc[i][j] = __builtin_amdgcn_mfma_f32_16x16x32_bf16(afr[i], bfr[j], acc[i][j], 0, 0, 0);
  }
}

// ---- variant: A is fp32 (converted to bf16 during staging), B bf16 full ----
__device__ __forceinline__ void gemm_bt_tile_f32A(
    const float* __restrict__ A, long lda,
    const unsigned short* __restrict__ B, long ldb,
    int Kd, unsigned short* lA, unsigned short* lB, f32x4_t acc[4][4]) {
  const int tid = threadIdx.x;
  const int lane = tid & 63;
  const int wid = tid >> 6;
  const int wm = wid >> 1, wn = wid & 1;
  const int lr = lane & 15, quad = lane >> 4;
  for (int ks = 0; ks < Kd; ks += 32) {
    __syncthreads();
#pragma unroll
    for (int c = 0; c < 2; ++c) {
      int chunk = tid + c * 256;
      int row = chunk >> 2;
      int kc = (chunk & 3) << 3;
      const float* ap = A + (long)row * lda + ks + kc;
      float4 f0 = *(const float4*)ap;
      float4 f1 = *(const float4*)(ap + 4);
      ushort8_t va;
      va[0] = f2bf(f0.x); va[1] = f2bf(f0.y); va[2] = f2bf(f0.z); va[3] = f2bf(f0.w);
      va[4] = f2bf(f1.x); va[5] = f2bf(f1.y); va[6] = f2bf(f1.z); va[7] = f2bf(f1.w);
      *(ushort8_t*)(lA + row * LDS_STRIDE + kc) = va;
      ushort8_t vb = *(const ushort8_t*)(B + (long)row * ldb + ks + kc);
      *(ushort8_t*)(lB + row * LDS_STRIDE + kc) = vb;
    }
    __syncthreads();
    bf16x8_t afr[4], bfr[4];
#pragma unroll
    for (int i = 0; i < 4; ++i)
      afr[i] = *(const bf16x8_t*)(lA + (wm * 64 + i * 16 + lr) * LDS_STRIDE + quad * 8);
#pragma unroll
    for (int j = 0; j < 4; ++j)
      bfr[j] = *(const bf16x8_t*)(lB + (wn * 64 + j * 16 + lr) * LDS_STRIDE + quad * 8);
#pragma unroll
    for (int i = 0; i < 4; ++i)
#pragma unroll
      for (int j = 0; j < 4; ++j)
        acc[i][j] = __builtin_amdgcn_mfma_f32_16x16x32_bf16(afr[i], bfr[j], acc[i][j], 0, 0, 0);
  }
}

#define EPILOGUE_IDX()                                          \
  const int tid = threadIdx.x, lane = tid & 63, wid = tid >> 6; \
  const int wm = wid >> 1, wn = wid & 1, lr = lane & 15, quad = lane >> 4;

#define ACC_INIT()            \
  f32x4_t acc[4][4];          \
  _Pragma("unroll") for (int i = 0; i < 4; ++i)     \
  _Pragma("unroll") for (int j = 0; j < 4; ++j)     \
  _Pragma("unroll") for (int r = 0; r < 4; ++r) acc[i][j][r] = 0.f;

// ---- projection: C_bf16 = bf16(A_f32 @ Wt^T + bias), N=1024 ---------------
__global__ __launch_bounds__(256) void k_proj(const float* __restrict__ A,
                                              const unsigned short* __restrict__ Wt,
                                              const float* __restrict__ bias,
                                              unsigned short* __restrict__ C) {
  __shared__ __attribute__((aligned(16))) unsigned short lA[128 * LDS_STRIDE];
  __shared__ __attribute__((aligned(16))) unsigned short lB[128 * LDS_STRIDE];
  ACC_INIT();
  const float* Ab = A + (long)blockIdx.y * 128 * 1024;
  const unsigned short* Bb = Wt + (long)blockIdx.x * 128 * 1024;
  gemm_bt_tile_f32A(Ab, 1024, Bb, 1024, 1024, lA, lB, acc);
  EPILOGUE_IDX();
  long mbase = (long)blockIdx.y * 128;
  int nbase = blockIdx.x * 128;
#pragma unroll
  for (int j = 0; j < 4; ++j) {
    int cg = nbase + wn * 64 + j * 16 + lr;
    float bvv = bias[cg];
#pragma unroll
    for (int i = 0; i < 4; ++i)
#pragma unroll
      for (int r = 0; r < 4; ++r) {
        long mg = mbase + wm * 64 + i * 16 + quad * 4 + r;
        C[mg * 1024 + cg] = f2bf(acc[i][j][r] + bvv);
      }
  }
}

// ---- attention scores -> bf16. is_ma: sigmoid(e/32+r) masked; else e/32|NEG.
__global__ __launch_bounds__(256) void k_escore(const unsigned short* __restrict__ qproj,
                                                const unsigned short* __restrict__ kproj,
                                                const int* __restrict__ mask,
                                                const float* __restrict__ rptr,
                                                unsigned short* __restrict__ outp, int is_ma) {
  __shared__ __attribute__((aligned(16))) unsigned short lA[128 * LDS_STRIDE];
  __shared__ __attribute__((aligned(16))) unsigned short lB[128 * LDS_STRIDE];
  ACC_INIT();
  int bz = blockIdx.z, b = bz >> 2, h = bz & 3;
  int nrow0 = blockIdx.x * 128;
  const unsigned short* Ab = qproj + ((long)b * 256 + blockIdx.y * 128) * 1024 + h * 256;
  const unsigned short* Bb = kproj + ((long)b * 2000 + nrow0) * 1024 + h * 256;
  int bval = 2000 - nrow0;
  if (bval > 128) bval = 128;
  if (bval < 0) bval = 0;
  gemm_bt_tile(Ab, 1024, Bb, 1024, bval, 256, lA, lB, acc);
  float rv = is_ma ? rptr[0] : 0.f;
  EPILOGUE_IDX();
#pragma unroll
  for (int j = 0; j < 4; ++j) {
    int kg = nrow0 + wn * 64 + j * 16 + lr;
#pragma unroll
    for (int i = 0; i < 4; ++i)
#pragma unroll
      for (int r = 0; r < 4; ++r) {
        int qg = blockIdx.y * 128 + wm * 64 + i * 16 + quad * 4 + r;
        float e = acc[i][j][r] * 0.03125f;
        bool valid = false;
        if (kg < 2000) valid = (mask[((long)b * 256 + qg) * 2000 + kg] != 0);
        float ov;
        if (is_ma)
          ov = valid ? (1.f / (1.f + __expf(-(e + rv)))) : 0.f;
        else
          ov = valid ? e : -1e9f;
        outp[((long)bz * 256 + qg) * 2048 + kg] = f2bf(ov);
      }
  }
}

// ---- cp = exp(exclusive_cumsum_k(log(clip(1-p)))), bf16 out, parallel -----
__global__ __launch_bounds__(256) void k_cp(const unsigned short* __restrict__ p,
                                            unsigned short* __restrict__ cp) {
  __shared__ float wsum[4];
  long base = (long)blockIdx.x * 2048;
  int tid = threadIdx.x, lane = tid & 63, wid = tid >> 6;
  ushort8_t p8 = *(const ushort8_t*)(p + base + tid * 8);
  float lex[8], s1 = 0.f;
#pragma unroll
  for (int i = 0; i < 8; ++i) {
    float om = fminf(fmaxf(1.f - bf2f((unsigned short)p8[i]), 1e-6f), 1.f);
    lex[i] = s1;
    s1 += __logf(om);
  }
  float incl = wave_incl_scan(s1);
  if (lane == 63) wsum[wid] = incl;
  __syncthreads();
  float off = incl - s1;
  if (wid > 0) off += wsum[0];
  if (wid > 1) off += wsum[1];
  if (wid > 2) off += wsum[2];
  ushort8_t o;
#pragma unroll
  for (int i = 0; i < 8; ++i) o[i] = f2bf(__expf(off + lex[i]));
  *(ushort8_t*)(cp + base + tid * 8) = o;
}

// ---- sequential scan over q; cp precomputed; aw state fp32 regs -----------
// per q: aw_new[k] = p[k]*cp[k] * prefix_k(aw[k]/clip(cp[k]))
__global__ __launch_bounds__(256) void k_scan(const unsigned short* __restrict__ p,
                                              const unsigned short* __restrict__ cp,
                                              const float* __restrict__ awp,
                                              unsigned short* __restrict__ alpha) {
  __shared__ float wsum[2][4];
  int bh = blockIdx.x;
  int tid = threadIdx.x, lane = tid & 63, wid = tid >> 6;
  long base = (long)bh * 256 * 2048 + tid * 8;
  float aw[8];
  const float* ap = awp + (long)bh * 2000;
#pragma unroll
  for (int i = 0; i < 8; ++i) {
    int k = tid * 8 + i;
    aw[i] = (k < 2000) ? ap[k] : 0.f;
  }
  const unsigned short* prow = p + base;
  const unsigned short* crow = cp + base;
  unsigned short* arow = alpha + base;
  ushort8_t pcur = *(const ushort8_t*)prow;
  ushort8_t ccur = *(const ushort8_t*)crow;
  for (int q = 0; q < 256; ++q) {
    ushort8_t pnext = pcur, cnext = ccur;
    if (q < 255) {
      pnext = *(const ushort8_t*)(prow + (long)(q + 1) * 2048);
      cnext = *(const ushort8_t*)(crow + (long)(q + 1) * 2048);
    }
    // q-local precompute (independent of the aw recursion)
    float pc[8], rd[8];
#pragma unroll
    for (int i = 0; i < 8; ++i) {
      float pv = bf2f((unsigned short)pcur[i]);
      float cv = bf2f((unsigned short)ccur[i]);
      pc[i] = pv * cv;
      rd[i] = __builtin_amdgcn_rcpf(fminf(fmaxf(cv, 1e-6f), 1.f));
    }
    // serial intra-thread prefix of aw*rd
    float t[8], s = 0.f;
#pragma unroll
    for (int i = 0; i < 8; ++i) {
      s = fmaf(aw[i], rd[i], s);
      t[i] = s;
    }
    // cross-lane inclusive scan of thread sums (DPP), then cross-wave via LDS
    float incl = wave_incl_scan(s);
    if (lane == 63) wsum[q & 1][wid] = incl;
    __syncthreads();
    float off = incl - s;
    if (wid > 0) off += wsum[q & 1][0];
    if (wid > 1) off += wsum[q & 1][1];
    if (wid > 2) off += wsum[q & 1][2];
    ushort8_t o;
#pragma unroll
    for (int i = 0; i < 8; ++i) {
      aw[i] = pc[i] * (t[i] + off);
      o[i] = f2bf(aw[i]);
    }
    *(ushort8_t*)(arow + (long)q * 2048) = o;
    pcur = pnext;
    ccur = cnext;
  }
}

// ---- beta = se * movsum_fwd7(alpha / movsum_back7(se)); in-place over eca --
__global__ __launch_bounds__(256) void k_beta(unsigned short* __restrict__ eca,
                                              const unsigned short* __restrict__ alpha) {
  __shared__ float sse[2048];
  __shared__ float sra[2048];
  __shared__ float red[4];
  long base = (long)blockIdx.x * 2048;
  int tid = threadIdx.x, lane = tid & 63, wid = tid >> 6;
  ushort8_t u8 = *(const ushort8_t*)(eca + base + tid * 8);
  ushort8_t a8 = *(const ushort8_t*)(alpha + base + tid * 8);
  float u[8], a[8];
#pragma unroll
  for (int i = 0; i < 8; ++i) {
    u[i] = bf2f((unsigned short)u8[i]);
    a[i] = bf2f((unsigned short)a8[i]);
  }
  float m = u[0];
#pragma unroll
  for (int i = 1; i < 8; ++i) m = fmaxf(m, u[i]);
  for (int d = 1; d < 64; d <<= 1) m = fmaxf(m, __shfl_xor(m, d, 64));
  if (lane == 0) red[wid] = m;
  __syncthreads();
  m = fmaxf(fmaxf(red[0], red[1]), fmaxf(red[2], red[3]));
  float se[8];
#pragma unroll
  for (int i = 0; i < 8; ++i) {
    se[i] = fmaxf(__expf(u[i] - m), 1e-5f);
    sse[tid * 8 + i] = se[i];
  }
  __syncthreads();
#pragma unroll
  for (int i = 0; i < 8; ++i) {
    int k = tid * 8 + i;
    float s = 0.f;
#pragma unroll
    for (int dd = 0; dd < 8; ++dd) {
      int j = k - dd;
      if (j >= 0) s += sse[j];
    }
    sra[k] = a[i] * __builtin_amdgcn_rcpf(s);
  }
  __syncthreads();
  ushort8_t o;
#pragma unroll
  for (int i = 0; i < 8; ++i) {
    int k = tid * 8 + i;
    float s = 0.f;
#pragma unroll
    for (int dd = 0; dd < 8; ++dd) {
      int j = k + dd;
      if (j <= 2047) s += sra[j];
    }
    o[i] = f2bf(se[i] * s);
  }
  *(ushort8_t*)(eca + base + tid * 8) = o;
}

// ---- vT[bz][d][k] = vproj[b*2000+k][h*256+d], k pad 2048 ------------------
__global__ __launch_bounds__(256) void k_build_vT(const unsigned short* __restrict__ v,
                                                  unsigned short* __restrict__ vT) {
  __shared__ unsigned short t[64][72];
  int bz = blockIdx.z, b = bz >> 2, h = bz & 3;
  int k0 = blockIdx.x * 64, d0 = blockIdx.y * 64;
  int tx = threadIdx.x & 63, tg = threadIdx.x >> 6;
#pragma unroll
  for (int i = 0; i < 16; ++i) {
    int kk = tg * 16 + i;
    int k = k0 + kk;
    unsigned short val = 0;
    if (k < 2000) val = v[((long)(b * 2000 + k)) * 1024 + h * 256 + d0 + tx];
    t[kk][tx] = val;
  }
  __syncthreads();
#pragma unroll
  for (int i = 0; i < 16; ++i) {
    int dd = tg * 16 + i;
    vT[((long)bz * 256 + d0 + dd) * 2048 + k0 + tx] = t[tx][dd];
  }
}

// ---- cv = beta @ v (per bz: 256x2048 @ 2048x256), bf16 out ----------------
__global__ __launch_bounds__(256) void k_cv(const unsigned short* __restrict__ beta,
                                            const unsigned short* __restrict__ vT,
                                            unsigned short* __restrict__ cv) {
  __shared__ __attribute__((aligned(16))) unsigned short lA[128 * LDS_STRIDE];
  __shared__ __attribute__((aligned(16))) unsigned short lB[128 * LDS_STRIDE];
  ACC_INIT();
  int bz = blockIdx.z, b = bz >> 2, h = bz & 3;
  const unsigned short* Ab = beta + (long)bz * 256 * 2048 + (long)blockIdx.y * 128 * 2048;
  const unsigned short* Bb = vT + (long)bz * 256 * 2048 + (long)blockIdx.x * 128 * 2048;
  gemm_bt_tile(Ab, 2048, Bb, 2048, 128, 2048, lA, lB, acc);
  EPILOGUE_IDX();
#pragma unroll
  for (int j = 0; j < 4; ++j) {
    int cg = h * 256 + blockIdx.x * 128 + wn * 64 + j * 16 + lr;
#pragma unroll
    for (int i = 0; i < 4; ++i)
#pragma unroll
      for (int r = 0; r < 4; ++r) {
        long mg = (long)b * 256 + blockIdx.y * 128 + wm * 64 + i * 16 + quad * 4 + r;
        cv[mg * 1024 + cg] = f2bf(acc[i][j][r]);
      }
  }
}

// ---- out = cv @ WoT^T + bo, fp32, M=4096 N=1024 ---------------------------
__global__ __launch_bounds__(256) void k_out(const unsigned short* __restrict__ cv,
                                             const unsigned short* __restrict__ WoT,
                                             const float* __restrict__ bo,
                                             float* __restrict__ outp) {
  __shared__ __attribute__((aligned(16))) unsigned short lA[128 * LDS_STRIDE];
  __shared__ __attribute__((aligned(16))) unsigned short lB[128 * LDS_STRIDE];
  ACC_INIT();
  const unsigned short* Ab = cv + (long)blockIdx.y * 128 * 1024;
  const unsigned short* Bb = WoT + (long)blockIdx.x * 128 * 1024;
  gemm_bt_tile(Ab, 1024, Bb, 1024, 128, 1024, lA, lB, acc);
  EPILOGUE_IDX();
#pragma unroll
  for (int j = 0; j < 4; ++j) {
    int cg = blockIdx.x * 128 + wn * 64 + j * 16 + lr;
    float bvv = bo[cg];
#pragma unroll
    for (int i = 0; i < 4; ++i)
#pragma unroll
      for (int r = 0; r < 4; ++r) {
        long mg = (long)blockIdx.y * 128 + wm * 64 + i * 16 + quad * 4 + r;
        outp[mg * 1024 + cg] = acc[i][j][r] + bvv;
      }
  }
}

// ---- W(1024x1024 f32) -> Wt bf16, Wt[n][d] = W[d][n] ----------------------
__global__ __launch_bounds__(256) void k_twT(const float* __restrict__ W,
                                             unsigned short* __restrict__ Wt) {
  __shared__ float t[32][33];
  int bx = blockIdx.x, by = blockIdx.y;
  int lx = threadIdx.x & 31, ly = threadIdx.x >> 5;
#pragma unroll
  for (int r = 0; r < 4; ++r)
    t[ly + 8 * r][lx] = W[((long)(by * 32 + ly + 8 * r)) * 1024 + bx * 32 + lx];
  __syncthreads();
#pragma unroll
  for (int r = 0; r < 4; ++r)
    Wt[((long)(bx * 32 + ly + 8 * r)) * 1024 + by * 32 + lx] = f2bf(t[lx][ly + 8 * r]);
}

// ---------------------------------------------------------------------------
extern "C" void kernel_launch(void* const* d_in, const int* in_sizes, int n_in,
                              void* d_out, int out_size, void* d_ws, size_t ws_size,
                              hipStream_t stream) {
  const float* key = (const float*)d_in[0];
  const float* value = (const float*)d_in[1];
  const float* query = (const float*)d_in[2];
  const int* mask = (const int*)d_in[3];
  const float* awp = (const float*)d_in[4];
  const float* Wk_ma = (const float*)d_in[5];
  const float* bk_ma = (const float*)d_in[6];
  const float* Wq_ma = (const float*)d_in[7];
  const float* bq_ma = (const float*)d_in[8];
  const float* rvec = (const float*)d_in[9];
  const float* Wk_ca = (const float*)d_in[10];
  const float* bk_ca = (const float*)d_in[11];
  const float* Wq_ca = (const float*)d_in[12];
  const float* bq_ca = (const float*)d_in[13];
  const float* Wv = (const float*)d_in[14];
  const float* bv = (const float*)d_in[15];
  const float* Wo = (const float*)d_in[16];
  const float* bo = (const float*)d_in[17];
  float* outp = (float*)d_out;
  (void)in_sizes; (void)n_in; (void)out_size;

  // workspace arena, ~219 MiB total
  char* ws = (char*)d_ws;
  size_t off = 0;
  auto alloc = [&](size_t bytes) {
    void* pp = ws + off;
    off += (bytes + 255) & ~(size_t)255;
    return pp;
  };
  unsigned short* wt[6];
  for (int i = 0; i < 6; ++i) wt[i] = (unsigned short*)alloc(1024L * 1024 * 2);
  unsigned short* kproj = (unsigned short*)alloc(32000L * 1024 * 2);  // k_ma -> cp -> k_ca -> v
  unsigned short* qproj = (unsigned short*)alloc(4096L * 1024 * 2);   // q_ma -> (cp tail) -> q_ca
  unsigned short* bufP = (unsigned short*)alloc(64L * 256 * 2048 * 2);  // p -> eca -> beta
  unsigned short* bufA = (unsigned short*)alloc(64L * 256 * 2048 * 2);  // alpha -> vT
  unsigned short* cv_bf = (unsigned short*)alloc(4096L * 1024 * 2);
  if (ws_size < off) return;  // ws too small: fail via absmax, not a fault
  // cp (64 MiB bf16) aliases the dead kproj+qproj region between k_cp and
  // the CA projections (k_ma/q_ma are consumed by the first k_escore).
  unsigned short* cpbuf = kproj;

  dim3 blk(256);
  // weights
  k_twT<<<dim3(32, 32), blk, 0, stream>>>(Wk_ma, wt[0]);
  k_twT<<<dim3(32, 32), blk, 0, stream>>>(Wq_ma, wt[1]);
  k_twT<<<dim3(32, 32), blk, 0, stream>>>(Wk_ca, wt[2]);
  k_twT<<<dim3(32, 32), blk, 0, stream>>>(Wq_ca, wt[3]);
  k_twT<<<dim3(32, 32), blk, 0, stream>>>(Wv, wt[4]);
  k_twT<<<dim3(32, 32), blk, 0, stream>>>(Wo, wt[5]);
  // MA: projections -> p -> cp -> scan -> alpha
  k_proj<<<dim3(8, 250), blk, 0, stream>>>(key, wt[0], bk_ma, kproj);
  k_proj<<<dim3(8, 32), blk, 0, stream>>>(query, wt[1], bq_ma, qproj);
  k_escore<<<dim3(16, 2, 64), blk, 0, stream>>>(qproj, kproj, mask, rvec, bufP, 1);
  k_cp<<<dim3(16384), blk, 0, stream>>>(bufP, cpbuf);
  k_scan<<<dim3(64), blk, 0, stream>>>(bufP, cpbuf, awp, bufA);
  // CA: projections (overwrite cp region) -> eca (reuses bufP) -> beta
  k_proj<<<dim3(8, 250), blk, 0, stream>>>(key, wt[2], bk_ca, kproj);
  k_proj<<<dim3(8, 32), blk, 0, stream>>>(query, wt[3], bq_ca, qproj);
  k_escore<<<dim3(16, 2, 64), blk, 0, stream>>>(qproj, kproj, mask, rvec, bufP, 0);
  k_beta<<<dim3(16384), blk, 0, stream>>>(bufP, bufA);
  // value path (vT reuses bufA after alpha consumed)
  k_proj<<<dim3(8, 250), blk, 0, stream>>>(value, wt[4], bv, kproj);
  k_build_vT<<<dim3(32, 4, 64), blk, 0, stream>>>(kproj, bufA);
  // context + output
  k_cv<<<dim3(2, 2, 64), blk, 0, stream>>>(bufP, bufA, cv_bf);
  k_out<<<dim3(8, 32), blk, 0, stream>>>(cv_bf, wt[5], bo, outp);
}

// Round 4
// 1326.270 us; speedup vs baseline: 1.3906x; 1.2860x over previous
//
#include <hip/hip_runtime.h>

// ---------------------------------------------------------------------------
// MoChA monotonic chunkwise attention. B=16, K=2000(pad 2048), Q=256, D=1024,
// H=4, dk=256, W=8, SCALE=32.
// R4: (1) all GEMMs use m97-style global_load_lds(16B) staging with bf16
// pre-converted, zero-padded inputs (stride-32 LDS, no predication);
// (2) XCD swizzle on k_proj so the 8 n-tiles sharing an A-tile land on one
// XCD (R3: FETCH 516MB vs 131MB ideal = cross-XCD refetch);
// (3) k_beta rewritten: register/DPP W=8 moving sums (R3: 9.9e7 bank
// conflicts from stride-8 scalar LDS).
// Arena 284 MiB, ws_size-guarded.
// ---------------------------------------------------------------------------

typedef __bf16 bf16x8_t __attribute__((ext_vector_type(8)));
typedef float f32x4_t __attribute__((ext_vector_type(4)));
typedef unsigned short ushort8_t __attribute__((ext_vector_type(8)));

__device__ __forceinline__ unsigned short f2bf(float x) {
  unsigned int u = __builtin_bit_cast(unsigned int, x);
  u += 0x7fffu + ((u >> 16) & 1u);  // RNE
  return (unsigned short)(u >> 16);
}
__device__ __forceinline__ float bf2f(unsigned short h) {
  unsigned int u = ((unsigned int)h) << 16;
  return __builtin_bit_cast(float, u);
}

// async 16B/lane global->LDS; lds dest must be wave-uniform base (+lane*16)
__device__ __forceinline__ void gld16(const unsigned short* g, unsigned short* l) {
  __builtin_amdgcn_global_load_lds(
      (const __attribute__((address_space(1))) void*)g,
      (__attribute__((address_space(3))) void*)l, 16, 0, 0);
}

// 64-lane inclusive prefix sum, 6 DPP steps (validated R3)
__device__ __forceinline__ float wave_incl_scan(float x) {
  float v = x;
  int mv;
#define DPP_ADD(ctrl, rmask, bctrl)                                           \
  mv = __builtin_amdgcn_update_dpp(0, __builtin_bit_cast(int, v), ctrl,       \
                                   rmask, 0xf, bctrl);                        \
  v += __builtin_bit_cast(float, mv);
  DPP_ADD(0x111, 0xf, true);   // row_shr:1
  DPP_ADD(0x112, 0xf, true);   // row_shr:2
  DPP_ADD(0x114, 0xf, true);   // row_shr:4
  DPP_ADD(0x118, 0xf, true);   // row_shr:8
  DPP_ADD(0x142, 0xa, false);  // bcast15 -> rows 1,3
  DPP_ADD(0x143, 0xc, false);  // bcast31 -> rows 2,3
#undef DPP_ADD
  return v;
}

// wave max, broadcast to all lanes
__device__ __forceinline__ float wave_max_bcast(float x) {
  const float NI = -__builtin_inff();
  float v = x;
  int mv;
#define DPP_MAX(ctrl, rmask)                                                  \
  mv = __builtin_amdgcn_update_dpp(__builtin_bit_cast(int, NI),               \
                                   __builtin_bit_cast(int, v), ctrl, rmask,   \
                                   0xf, false);                               \
  v = fmaxf(v, __builtin_bit_cast(float, mv));
  DPP_MAX(0x111, 0xf) DPP_MAX(0x112, 0xf) DPP_MAX(0x114, 0xf)
  DPP_MAX(0x118, 0xf) DPP_MAX(0x142, 0xa) DPP_MAX(0x143, 0xc)
#undef DPP_MAX
  int r = __builtin_amdgcn_readlane(__builtin_bit_cast(int, v), 63);
  return __builtin_bit_cast(float, r);
}

#define WSHR1(dst, src)                                                       \
  {                                                                           \
    int _t = __builtin_amdgcn_update_dpp(0, __builtin_bit_cast(int, src),     \
                                         0x138, 0xf, 0xf, true);              \
    dst = __builtin_bit_cast(float, _t);                                      \
  }
#define WSHL1(dst, src)                                                       \
  {                                                                           \
    int _t = __builtin_amdgcn_update_dpp(0, __builtin_bit_cast(int, src),     \
                                         0x130, 0xf, 0xf, true);              \
    dst = __builtin_bit_cast(float, _t);                                      \
  }

// ---- core 128x128 MFMA tile, async staging, all rows valid ----------------
__device__ __forceinline__ void gemm_bt_tile(
    const unsigned short* __restrict__ A, long lda,
    const unsigned short* __restrict__ B, long ldb,
    int Kd, unsigned short* lA, unsigned short* lB, f32x4_t acc[4][4]) {
  const int tid = threadIdx.x;
  const int lane = tid & 63;
  const int wid = tid >> 6;
  const int wm = wid >> 1, wn = wid & 1;
  const int lr = lane & 15, quad = lane >> 4;
  const int srow = wid * 32 + (lane >> 2);  // staging row, this wave: +0 / +16
  const int scol = (lane & 3) * 8;          // staging elem col
  for (int ks = 0; ks < Kd; ks += 32) {
    __syncthreads();  // protect LDS against previous slab's readers
    gld16(A + (long)srow * lda + ks + scol, lA + (wid * 32) * 32);
    gld16(A + (long)(srow + 16) * lda + ks + scol, lA + (wid * 32 + 16) * 32);
    gld16(B + (long)srow * ldb + ks + scol, lB + (wid * 32) * 32);
    gld16(B + (long)(srow + 16) * ldb + ks + scol, lB + (wid * 32 + 16) * 32);
    __syncthreads();  // drains vmcnt -> staged data visible
    bf16x8_t afr[4], bfr[4];
#pragma unroll
    for (int i = 0; i < 4; ++i)
      afr[i] = *(const bf16x8_t*)(lA + (wm * 64 + i * 16 + lr) * 32 + quad * 8);
#pragma unroll
    for (int j = 0; j < 4; ++j)
      bfr[j] = *(const bf16x8_t*)(lB + (wn * 64 + j * 16 + lr) * 32 + quad * 8);
#pragma unroll
    for (int i = 0; i < 4; ++i)
#pragma unroll
      for (int j = 0; j < 4; ++j)
        acc[i][j] = __builtin_amdgcn_mfma_f32_16x16x32_bf16(afr[i], bfr[j], acc[i][j], 0, 0, 0);
  }
}

#define EPILOGUE_IDX()                                          \
  const int tid = threadIdx.x, lane = tid & 63, wid = tid >> 6; \
  const int wm = wid >> 1, wn = wid & 1, lr = lane & 15, quad = lane >> 4;

#define ACC_INIT()                              \
  f32x4_t acc[4][4];                            \
  _Pragma("unroll") for (int i = 0; i < 4; ++i) \
  _Pragma("unroll") for (int j = 0; j < 4; ++j) \
  _Pragma("unroll") for (int r = 0; r < 4; ++r) acc[i][j][r] = 0.f;

// ---- projection: C_bf16 = bf16(A_bf @ Wt^T + bias), N=1024, 1D swizzled ---
// flat -> group of 64 blocks = 8 m-rows x 8 n; flat%8 = m_local so all 8
// n-tiles of one m-row share an XCD (dispatch round-robin over 8 XCDs).
__global__ __launch_bounds__(256) void k_proj(const unsigned short* __restrict__ A,
                                              const unsigned short* __restrict__ Wt,
                                              const float* __restrict__ bias,
                                              unsigned short* __restrict__ C) {
  __shared__ __attribute__((aligned(16))) unsigned short lA[128 * 32];
  __shared__ __attribute__((aligned(16))) unsigned short lB[128 * 32];
  ACC_INIT();
  int flat = blockIdx.x;
  int mb = (flat >> 6) * 8 + (flat & 7);
  int nb = (flat >> 3) & 7;
  const unsigned short* Ab = A + (long)mb * 128 * 1024;
  const unsigned short* Bb = Wt + (long)nb * 128 * 1024;
  gemm_bt_tile(Ab, 1024, Bb, 1024, 1024, lA, lB, acc);
  EPILOGUE_IDX();
  long mbase = (long)mb * 128;
  int nbase = nb * 128;
#pragma unroll
  for (int j = 0; j < 4; ++j) {
    int cg = nbase + wn * 64 + j * 16 + lr;
    float bvv = bias[cg];
#pragma unroll
    for (int i = 0; i < 4; ++i)
#pragma unroll
      for (int r = 0; r < 4; ++r) {
        long mg = mbase + wm * 64 + i * 16 + quad * 4 + r;
        C[mg * 1024 + cg] = f2bf(acc[i][j][r] + bvv);
      }
  }
}

// ---- attention scores -> bf16. kproj padded to 2048 rows/batch ------------
__global__ __launch_bounds__(256) void k_escore(const unsigned short* __restrict__ qproj,
                                                const unsigned short* __restrict__ kproj,
                                                const int* __restrict__ mask,
                                                const float* __restrict__ rptr,
                                                unsigned short* __restrict__ outp, int is_ma) {
  __shared__ __attribute__((aligned(16))) unsigned short lA[128 * 32];
  __shared__ __attribute__((aligned(16))) unsigned short lB[128 * 32];
  ACC_INIT();
  int bz = blockIdx.z, b = bz >> 2, h = bz & 3;
  int nrow0 = blockIdx.x * 128;
  const unsigned short* Ab = qproj + ((long)b * 256 + blockIdx.y * 128) * 1024 + h * 256;
  const unsigned short* Bb = kproj + ((long)b * 2048 + nrow0) * 1024 + h * 256;
  gemm_bt_tile(Ab, 1024, Bb, 1024, 256, lA, lB, acc);
  float rv = is_ma ? rptr[0] : 0.f;
  EPILOGUE_IDX();
#pragma unroll
  for (int j = 0; j < 4; ++j) {
    int kg = nrow0 + wn * 64 + j * 16 + lr;
#pragma unroll
    for (int i = 0; i < 4; ++i)
#pragma unroll
      for (int r = 0; r < 4; ++r) {
        int qg = blockIdx.y * 128 + wm * 64 + i * 16 + quad * 4 + r;
        float e = acc[i][j][r] * 0.03125f;
        bool valid = false;
        if (kg < 2000) valid = (mask[((long)b * 256 + qg) * 2000 + kg] != 0);
        float ov;
        if (is_ma)
          ov = valid ? (1.f / (1.f + __expf(-(e + rv)))) : 0.f;
        else
          ov = valid ? e : -1e9f;
        outp[((long)bz * 256 + qg) * 2048 + kg] = f2bf(ov);
      }
  }
}

// ---- cp = exp(exclusive_cumsum_k(log(clip(1-p)))), bf16, parallel ---------
__global__ __launch_bounds__(256) void k_cp(const unsigned short* __restrict__ p,
                                            unsigned short* __restrict__ cp) {
  __shared__ float wsum[4];
  long base = (long)blockIdx.x * 2048;
  int tid = threadIdx.x, lane = tid & 63, wid = tid >> 6;
  ushort8_t p8 = *(const ushort8_t*)(p + base + tid * 8);
  float lex[8], s1 = 0.f;
#pragma unroll
  for (int i = 0; i < 8; ++i) {
    float om = fminf(fmaxf(1.f - bf2f((unsigned short)p8[i]), 1e-6f), 1.f);
    lex[i] = s1;
    s1 += __logf(om);
  }
  float incl = wave_incl_scan(s1);
  if (lane == 63) wsum[wid] = incl;
  __syncthreads();
  float off = incl - s1;
  if (wid > 0) off += wsum[0];
  if (wid > 1) off += wsum[1];
  if (wid > 2) off += wsum[2];
  ushort8_t o;
#pragma unroll
  for (int i = 0; i < 8; ++i) o[i] = f2bf(__expf(off + lex[i]));
  *(ushort8_t*)(cp + base + tid * 8) = o;
}

// ---- sequential scan over q; cp MAY ALIAS alpha (row read before write) ---
__global__ __launch_bounds__(256) void k_scan(const unsigned short* __restrict__ p,
                                              const unsigned short* cp,
                                              const float* __restrict__ awp,
                                              unsigned short* alpha) {
  __shared__ float wsum[2][4];
  int bh = blockIdx.x;
  int tid = threadIdx.x, lane = tid & 63, wid = tid >> 6;
  long base = (long)bh * 256 * 2048 + tid * 8;
  float aw[8];
  const float* ap = awp + (long)bh * 2000;
#pragma unroll
  for (int i = 0; i < 8; ++i) {
    int k = tid * 8 + i;
    aw[i] = (k < 2000) ? ap[k] : 0.f;
  }
  const unsigned short* prow = p + base;
  const unsigned short* crow = cp + base;
  unsigned short* arow = alpha + base;
  ushort8_t pcur = *(const ushort8_t*)prow;
  ushort8_t ccur = *(const ushort8_t*)crow;
  for (int q = 0; q < 256; ++q) {
    ushort8_t pnext = pcur, cnext = ccur;
    if (q < 255) {
      pnext = *(const ushort8_t*)(prow + (long)(q + 1) * 2048);
      cnext = *(const ushort8_t*)(crow + (long)(q + 1) * 2048);
    }
    float pc[8], rd[8];
#pragma unroll
    for (int i = 0; i < 8; ++i) {
      float pv = bf2f((unsigned short)pcur[i]);
      float cv = bf2f((unsigned short)ccur[i]);
      pc[i] = pv * cv;
      rd[i] = __builtin_amdgcn_rcpf(fminf(fmaxf(cv, 1e-6f), 1.f));
    }
    float t[8], s = 0.f;
#pragma unroll
    for (int i = 0; i < 8; ++i) {
      s = fmaf(aw[i], rd[i], s);
      t[i] = s;
    }
    float incl = wave_incl_scan(s);
    if (lane == 63) wsum[q & 1][wid] = incl;
    __syncthreads();
    float off = incl - s;
    if (wid > 0) off += wsum[q & 1][0];
    if (wid > 1) off += wsum[q & 1][1];
    if (wid > 2) off += wsum[q & 1][2];
    ushort8_t o;
#pragma unroll
    for (int i = 0; i < 8; ++i) {
      aw[i] = pc[i] * (t[i] + off);
      o[i] = f2bf(aw[i]);
    }
    *(ushort8_t*)(arow + (long)q * 2048) = o;
    pcur = pnext;
    ccur = cnext;
  }
}

// ---- beta = se * movsum_fwd7(alpha / movsum_back7(se)); register/DPP ------
__global__ __launch_bounds__(256) void k_beta(unsigned short* eca,
                                              const unsigned short* __restrict__ alpha) {
  __shared__ float red[4];
  __shared__ float edgeB[4][8];
  __shared__ float edgeF[4][8];
  long base = (long)blockIdx.x * 2048 + threadIdx.x * 8;
  int tid = threadIdx.x, lane = tid & 63, wid = tid >> 6;
  (void)tid;
  ushort8_t u8 = *(const ushort8_t*)(eca + base);
  ushort8_t a8 = *(const ushort8_t*)(alpha + base);
  float u[8], a[8];
#pragma unroll
  for (int i = 0; i < 8; ++i) {
    u[i] = bf2f((unsigned short)u8[i]);
    a[i] = bf2f((unsigned short)a8[i]);
  }
  // block max
  float m = u[0];
#pragma unroll
  for (int i = 1; i < 8; ++i) m = fmaxf(m, u[i]);
  m = wave_max_bcast(m);
  if (lane == 0) red[wid] = m;
  __syncthreads();
  m = fmaxf(fmaxf(red[0], red[1]), fmaxf(red[2], red[3]));
  // se + local prefix lp
  float se[8], lp[8];
  float s = 0.f;
#pragma unroll
  for (int i = 0; i < 8; ++i) {
    se[i] = fmaxf(__expf(u[i] - m), 1e-5f);
    s += se[i];
    lp[i] = s;
  }
  // prev-lane lp (wave_shr:1), cross-wave patch via LDS
  float plp[8];
#pragma unroll
  for (int i = 0; i < 8; ++i) WSHR1(plp[i], lp[i]);
  if (lane == 63) {
#pragma unroll
    for (int i = 0; i < 8; ++i) edgeB[wid][i] = lp[i];
  }
  __syncthreads();
  if (lane == 0 && wid > 0) {
#pragma unroll
    for (int i = 0; i < 8; ++i) plp[i] = edgeB[wid - 1][i];
  }
  // msb = lp[i] + prevTotal - prevlp[i]; sra = a/msb; local prefix lf
  float sra[8], lf[8];
  s = 0.f;
#pragma unroll
  for (int i = 0; i < 8; ++i) {
    float msb = lp[i] + plp[7] - plp[i];
    sra[i] = a[i] * __builtin_amdgcn_rcpf(msb);
    s += sra[i];
    lf[i] = s;
  }
  // next-lane lf (wave_shl:1), cross-wave patch
  float nlf[8];
#pragma unroll
  for (int i = 0; i < 8; ++i) WSHL1(nlf[i], lf[i]);
  if (lane == 0) {
#pragma unroll
    for (int i = 0; i < 8; ++i) edgeF[wid][i] = lf[i];
  }
  __syncthreads();
  if (lane == 63 && wid < 3) {
#pragma unroll
    for (int i = 0; i < 8; ++i) nlf[i] = edgeF[wid + 1][i];
  }
  ushort8_t o;
#pragma unroll
  for (int i = 0; i < 8; ++i) {
    float own = lf[7] - (i ? lf[i - 1] : 0.f);
    float nxt = i ? nlf[i - 1] : 0.f;
    o[i] = f2bf(se[i] * (own + nxt));
  }
  *(ushort8_t*)(eca + base) = o;
}

// ---- vT[bz][d][k] = vproj[(b*2048+k)*1024 + h*256+d] ----------------------
__global__ __launch_bounds__(256) void k_build_vT(const unsigned short* __restrict__ v,
                                                  unsigned short* __restrict__ vT) {
  __shared__ unsigned short t[64][68];
  int bz = blockIdx.z, b = bz >> 2, h = bz & 3;
  int k0 = blockIdx.x * 64, d0 = blockIdx.y * 64;
  int tx = threadIdx.x & 63, tg = threadIdx.x >> 6;
#pragma unroll
  for (int i = 0; i < 16; ++i) {
    int kk = tg * 16 + i;
    t[kk][tx] = v[((long)(b * 2048 + k0 + kk)) * 1024 + h * 256 + d0 + tx];
  }
  __syncthreads();
#pragma unroll
  for (int i = 0; i < 16; ++i) {
    int dd = tg * 16 + i;
    vT[((long)bz * 256 + d0 + dd) * 2048 + k0 + tx] = t[tx][dd];
  }
}

// ---- cv = beta @ v (per bz: 256x2048 @ 2048x256), bf16 out ----------------
__global__ __launch_bounds__(256) void k_cv(const unsigned short* __restrict__ beta,
                                            const unsigned short* __restrict__ vT,
                                            unsigned short* __restrict__ cv) {
  __shared__ __attribute__((aligned(16))) unsigned short lA[128 * 32];
  __shared__ __attribute__((aligned(16))) unsigned short lB[128 * 32];
  ACC_INIT();
  int bz = blockIdx.z, b = bz >> 2, h = bz & 3;
  const unsigned short* Ab = beta + (long)bz * 256 * 2048 + (long)blockIdx.y * 128 * 2048;
  const unsigned short* Bb = vT + (long)bz * 256 * 2048 + (long)blockIdx.x * 128 * 2048;
  gemm_bt_tile(Ab, 2048, Bb, 2048, 2048, lA, lB, acc);
  EPILOGUE_IDX();
#pragma unroll
  for (int j = 0; j < 4; ++j) {
    int cg = h * 256 + blockIdx.x * 128 + wn * 64 + j * 16 + lr;
#pragma unroll
    for (int i = 0; i < 4; ++i)
#pragma unroll
      for (int r = 0; r < 4; ++r) {
        long mg = (long)b * 256 + blockIdx.y * 128 + wm * 64 + i * 16 + quad * 4 + r;
        cv[mg * 1024 + cg] = f2bf(acc[i][j][r]);
      }
  }
}

// ---- out = cv @ WoT^T + bo, fp32, M=4096 N=1024 ---------------------------
__global__ __launch_bounds__(256) void k_out(const unsigned short* __restrict__ cv,
                                             const unsigned short* __restrict__ WoT,
                                             const float* __restrict__ bo,
                                             float* __restrict__ outp) {
  __shared__ __attribute__((aligned(16))) unsigned short lA[128 * 32];
  __shared__ __attribute__((aligned(16))) unsigned short lB[128 * 32];
  ACC_INIT();
  const unsigned short* Ab = cv + (long)blockIdx.y * 128 * 1024;
  const unsigned short* Bb = WoT + (long)blockIdx.x * 128 * 1024;
  gemm_bt_tile(Ab, 1024, Bb, 1024, 1024, lA, lB, acc);
  EPILOGUE_IDX();
#pragma unroll
  for (int j = 0; j < 4; ++j) {
    int cg = blockIdx.x * 128 + wn * 64 + j * 16 + lr;
    float bvv = bo[cg];
#pragma unroll
    for (int i = 0; i < 4; ++i)
#pragma unroll
      for (int r = 0; r < 4; ++r) {
        long mg = (long)blockIdx.y * 128 + wm * 64 + i * 16 + quad * 4 + r;
        outp[mg * 1024 + cg] = acc[i][j][r] + bvv;
      }
  }
}

// ---- W(1024x1024 f32) -> Wt bf16, Wt[n][d] = W[d][n] ----------------------
__global__ __launch_bounds__(256) void k_twT(const float* __restrict__ W,
                                             unsigned short* __restrict__ Wt) {
  __shared__ float t[32][33];
  int bx = blockIdx.x, by = blockIdx.y;
  int lx = threadIdx.x & 31, ly = threadIdx.x >> 5;
#pragma unroll
  for (int r = 0; r < 4; ++r)
    t[ly + 8 * r][lx] = W[((long)(by * 32 + ly + 8 * r)) * 1024 + bx * 32 + lx];
  __syncthreads();
#pragma unroll
  for (int r = 0; r < 4; ++r)
    Wt[((long)(bx * 32 + ly + 8 * r)) * 1024 + by * 32 + lx] = f2bf(t[lx][ly + 8 * r]);
}

// ---- fp32 [16][2000][1024] -> bf16 [16][2048][1024], pads zero ------------
__global__ __launch_bounds__(256) void k_cvt_pad(const float* __restrict__ src,
                                                 unsigned short* __restrict__ dst) {
  long idx = (long)blockIdx.x * 256 + threadIdx.x;  // 8-elem chunks
  int b = (int)(idx >> 18);                         // 262144 chunks / batch
  int rem = (int)(idx & 262143);
  int row = rem >> 7;
  int c8 = rem & 127;
  ushort8_t o;
  if (row < 2000) {
    const float* sp = src + ((long)(b * 2000 + row)) * 1024 + c8 * 8;
    float4 f0 = *(const float4*)sp;
    float4 f1 = *(const float4*)(sp + 4);
    o[0] = f2bf(f0.x); o[1] = f2bf(f0.y); o[2] = f2bf(f0.z); o[3] = f2bf(f0.w);
    o[4] = f2bf(f1.x); o[5] = f2bf(f1.y); o[6] = f2bf(f1.z); o[7] = f2bf(f1.w);
  } else {
#pragma unroll
    for (int z = 0; z < 8; ++z) o[z] = 0;
  }
  *(ushort8_t*)(dst + idx * 8) = o;
}

// ---- fp32 -> bf16 plain (query) -------------------------------------------
__global__ __launch_bounds__(256) void k_cvt(const float* __restrict__ src,
                                             unsigned short* __restrict__ dst) {
  long idx = (long)blockIdx.x * 256 + threadIdx.x;
  const float* sp = src + idx * 8;
  float4 f0 = *(const float4*)sp;
  float4 f1 = *(const float4*)(sp + 4);
  ushort8_t o;
  o[0] = f2bf(f0.x); o[1] = f2bf(f0.y); o[2] = f2bf(f0.z); o[3] = f2bf(f0.w);
  o[4] = f2bf(f1.x); o[5] = f2bf(f1.y); o[6] = f2bf(f1.z); o[7] = f2bf(f1.w);
  *(ushort8_t*)(dst + idx * 8) = o;
}

// ---------------------------------------------------------------------------
extern "C" void kernel_launch(void* const* d_in, const int* in_sizes, int n_in,
                              void* d_out, int out_size, void* d_ws, size_t ws_size,
                              hipStream_t stream) {
  const float* key = (const float*)d_in[0];
  const float* value = (const float*)d_in[1];
  const float* query = (const float*)d_in[2];
  const int* mask = (const int*)d_in[3];
  const float* awp = (const float*)d_in[4];
  const float* Wk_ma = (const float*)d_in[5];
  const float* bk_ma = (const float*)d_in[6];
  const float* Wq_ma = (const float*)d_in[7];
  const float* bq_ma = (const float*)d_in[8];
  const float* rvec = (const float*)d_in[9];
  const float* Wk_ca = (const float*)d_in[10];
  const float* bk_ca = (const float*)d_in[11];
  const float* Wq_ca = (const float*)d_in[12];
  const float* bq_ca = (const float*)d_in[13];
  const float* Wv = (const float*)d_in[14];
  const float* bv = (const float*)d_in[15];
  const float* Wo = (const float*)d_in[16];
  const float* bo = (const float*)d_in[17];
  float* outp = (float*)d_out;
  (void)in_sizes; (void)n_in; (void)out_size;

  // arena, 284 MiB
  char* ws = (char*)d_ws;
  size_t off = 0;
  auto alloc = [&](size_t bytes) {
    void* pp = ws + off;
    off += (bytes + 255) & ~(size_t)255;
    return pp;
  };
  unsigned short* wt[6];
  for (int i = 0; i < 6; ++i) wt[i] = (unsigned short*)alloc(1024L * 1024 * 2);
  unsigned short* xbf = (unsigned short*)alloc(16L * 2048 * 1024 * 2);   // key_bf -> value_bf
  unsigned short* qbf = (unsigned short*)alloc(4096L * 1024 * 2);        // query_bf -> cv
  unsigned short* kproj = (unsigned short*)alloc(16L * 2048 * 1024 * 2); // k_ma -> k_ca -> v
  unsigned short* qproj = (unsigned short*)alloc(4096L * 1024 * 2);      // q_ma -> q_ca
  unsigned short* bufP = (unsigned short*)alloc(64L * 256 * 2048 * 2);   // p -> eca -> beta
  unsigned short* bufA = (unsigned short*)alloc(64L * 256 * 2048 * 2);   // cp -> alpha -> vT
  if (ws_size < off) return;  // fail via absmax, not a fault
  unsigned short* cv_bf = qbf;

  dim3 blk(256);
  // weights + input conversion
  k_twT<<<dim3(32, 32), blk, 0, stream>>>(Wk_ma, wt[0]);
  k_twT<<<dim3(32, 32), blk, 0, stream>>>(Wq_ma, wt[1]);
  k_twT<<<dim3(32, 32), blk, 0, stream>>>(Wk_ca, wt[2]);
  k_twT<<<dim3(32, 32), blk, 0, stream>>>(Wq_ca, wt[3]);
  k_twT<<<dim3(32, 32), blk, 0, stream>>>(Wv, wt[4]);
  k_twT<<<dim3(32, 32), blk, 0, stream>>>(Wo, wt[5]);
  k_cvt_pad<<<dim3(16384), blk, 0, stream>>>(key, xbf);
  k_cvt<<<dim3(2048), blk, 0, stream>>>(query, qbf);
  // MA path
  k_proj<<<dim3(2048), blk, 0, stream>>>(xbf, wt[0], bk_ma, kproj);
  k_proj<<<dim3(256), blk, 0, stream>>>(qbf, wt[1], bq_ma, qproj);
  k_escore<<<dim3(16, 2, 64), blk, 0, stream>>>(qproj, kproj, mask, rvec, bufP, 1);
  k_cp<<<dim3(16384), blk, 0, stream>>>(bufP, bufA);
  // CA projections (k_ma/q_ma dead; cp lives in bufA)
  k_proj<<<dim3(2048), blk, 0, stream>>>(xbf, wt[2], bk_ca, kproj);
  k_proj<<<dim3(256), blk, 0, stream>>>(qbf, wt[3], bq_ca, qproj);
  // scan: alpha overwrites cp row-by-row (read-before-write)
  k_scan<<<dim3(64), blk, 0, stream>>>(bufP, bufA, awp, bufA);
  // CA scores (p dead) + beta (in-place over eca)
  k_escore<<<dim3(16, 2, 64), blk, 0, stream>>>(qproj, kproj, mask, rvec, bufP, 0);
  k_beta<<<dim3(16384), blk, 0, stream>>>(bufP, bufA);
  // value path (key dead -> xbf reused; alpha dead -> bufA becomes vT)
  k_cvt_pad<<<dim3(16384), blk, 0, stream>>>(value, xbf);
  k_proj<<<dim3(2048), blk, 0, stream>>>(xbf, wt[4], bv, kproj);
  k_build_vT<<<dim3(32, 4, 64), blk, 0, stream>>>(kproj, bufA);
  // context + output
  k_cv<<<dim3(2, 2, 64), blk, 0, stream>>>(bufP, bufA, cv_bf);
  k_out<<<dim3(8, 32), blk, 0, stream>>>(cv_bf, wt[5], bo, outp);
}